// Round 4
// baseline (418.875 us; speedup 1.0000x reference)
//
#include <hip/hip_runtime.h>
#include <stdint.h>

// Problem constants (fixed by reference setup_inputs)
#define D_DIM 4096      // hidden dim (K)
#define E_NUM 64        // experts (N)
#define T_TOK 16384     // tokens (M) = 4*4096
#define CAPF 256.0f     // expert_capacity = int(16384/64*1.0)
#define ROWS 64         // tokens per block (M-tile) -> B traffic amortized 4x vs r2
#define NBLK (T_TOK / ROWS)   // 256 blocks of 512 thr -> 1 block/CU, 8 waves/CU

using bf16x8 = __attribute__((ext_vector_type(8))) short;
using f32x4  = __attribute__((ext_vector_type(4))) float;
typedef unsigned short u16;
typedef unsigned int u32;

// Truncation split: x == hi + lo exactly; lo then truncated to bf16 (err <= 2^-17 |x|).
__device__ __forceinline__ void cvt8(const float4 a, const float4 b, bf16x8& h, bf16x8& l) {
  float f[8] = {a.x, a.y, a.z, a.w, b.x, b.y, b.z, b.w};
#pragma unroll
  for (int i = 0; i < 8; ++i) {
    u32 u = __float_as_uint(f[i]);
    float lo = f[i] - __uint_as_float(u & 0xFFFF0000u);
    h[i] = (short)(u >> 16);
    l[i] = (short)(__float_as_uint(lo) >> 16);
  }
}

// Kernel 0: W (4096x64, [k][e]) -> Wp/Wlp packed in MFMA B-fragment order:
//   Wp[((kk*4 + ct)*64 + lane)*8 + i] = hi(W[kk*32 + (lane>>4)*8 + i][ct*16 + (lane&15)])
// so the GEMM's B-load is base + lane*16 (fully coalesced), no gathers.
__global__ __launch_bounds__(256) void prep_kernel(const float* __restrict__ W,
                                                   u16* __restrict__ Wp, u16* __restrict__ Wlp) {
  const int t = blockIdx.x * 256 + threadIdx.x;   // 32768 threads, one 16B chunk each
  const int lane = t & 63;
  const int ct = (t >> 6) & 3;
  const int kk = t >> 8;
  const int e = ct * 16 + (lane & 15);
  const int k0 = kk * 32 + (lane >> 4) * 8;
  u32 hp[4], lp[4];
#pragma unroll
  for (int j = 0; j < 4; ++j) {
    u32 hh[2], ll[2];
#pragma unroll
    for (int q = 0; q < 2; ++q) {
      float w = W[(size_t)(k0 + 2 * j + q) * E_NUM + e];
      u32 u = __float_as_uint(w);
      float lo = w - __uint_as_float(u & 0xFFFF0000u);
      hh[q] = u >> 16;
      ll[q] = __float_as_uint(lo) >> 16;
    }
    hp[j] = hh[0] | (hh[1] << 16);
    lp[j] = ll[0] | (ll[1] << 16);
  }
  *(uint4*)(Wp  + (size_t)t * 8) = make_uint4(hp[0], hp[1], hp[2], hp[3]);
  *(uint4*)(Wlp + (size_t)t * 8) = make_uint4(lp[0], lp[1], lp[2], lp[3]);
}

// Kernel 1: router GEMM + softmax + top-1.
// 64 tokens/block, 8 waves; wave kh owns K-range [kh*512, kh*512+512) = 16
// k32-chunks.  Theory r3: all prior versions plateaued at ~1KB/wave/1000cy
// because B was loaded with ZERO prefetch distance (wait for a just-issued
// load = vmcnt(0) drain, which in-order-drains the A HBM prefetch too ->
// one full memory latency per 12 MFMAs), and M_tile=16 made aggregate B
// traffic 1GB.  Here: B register-double-buffered (waits become counted),
// 48 MFMAs per k-chunk, B traffic 256MB total, A+B both 1 chunk ahead.
__global__ __launch_bounds__(512, 2) void gemm_softmax(
    const float* __restrict__ x, const u16* __restrict__ Wp, const u16* __restrict__ Wlp,
    const float* __restrict__ bias, float* __restrict__ out,
    float* __restrict__ Spart, float* __restrict__ Ppart,
    float* __restrict__ top_p, int* __restrict__ top_i) {
  __shared__ float slab[64 * 66];    // combined logits, [token][expert] stride 66 (16.9 KB)
  __shared__ float S_loc[64];        // per-block top-prob sums (LDS atomics)

  const int tid = threadIdx.x;
  const int lane = tid & 63;
  const int kh = tid >> 6;       // K-eighth (wave id) 0..7
  const int m = lane & 15;       // token-in-16-tile (A row)
  const int g = lane >> 4;       // k-octet
  const int tok_base = blockIdx.x * ROWS;

  // zero the combine slab + S_loc (covered by the pre-epilogue barrier)
  for (int i = tid; i < 64 * 66; i += 512) slab[i] = 0.f;
  if (tid < 64) S_loc[tid] = 0.f;

  f32x4 acc[4][4];               // [row-tile][col-tile] = 64 VGPRs
#pragma unroll
  for (int rt = 0; rt < 4; ++rt)
#pragma unroll
    for (int ct = 0; ct < 4; ++ct) acc[rt][ct] = (f32x4){0.f, 0.f, 0.f, 0.f};

  // A bases: row tok_base + rt*16 + m, col kh*512 + t*32 + g*8.
  const float* pa = x + (size_t)(tok_base + m) * D_DIM + kh * 512 + g * 8;
  // B base: byte offset ((kk32*4+ct)*64+lane)*16, kk32 = kh*16 + t.
  const size_t bbase = ((size_t)(kh * 16) * 4 * 64 + lane) * 8;

  float4 A0[4][2], A1[4][2];           // [rt][half] — named dbuf, static idx only
  bf16x8 Bh0[4], Bl0[4], Bh1[4], Bl1[4];

  auto loadA = [&](float4 (&dst)[4][2], int t) {
#pragma unroll
    for (int rt = 0; rt < 4; ++rt) {
      const float* q = pa + (size_t)rt * 16 * D_DIM + t * 32;
      dst[rt][0] = *(const float4*)(q);
      dst[rt][1] = *(const float4*)(q + 4);
    }
  };
  auto loadB = [&](bf16x8 (&bh)[4], bf16x8 (&bl)[4], int t) {
#pragma unroll
    for (int ct = 0; ct < 4; ++ct) {
      const size_t o = bbase + (size_t)(t * 4 + ct) * 64 * 8;
      bh[ct] = *(const bf16x8*)(Wp + o);
      bl[ct] = *(const bf16x8*)(Wlp + o);
    }
  };
  auto compute = [&](const float4 (&af)[4][2], const bf16x8 (&bh)[4], const bf16x8 (&bl)[4]) {
#pragma unroll
    for (int rt = 0; rt < 4; ++rt) {
      bf16x8 ah, al;
      cvt8(af[rt][0], af[rt][1], ah, al);
#pragma unroll
      for (int ct = 0; ct < 4; ++ct) {
        acc[rt][ct] = __builtin_amdgcn_mfma_f32_16x16x32_bf16(ah, bh[ct], acc[rt][ct], 0, 0, 0);
        acc[rt][ct] = __builtin_amdgcn_mfma_f32_16x16x32_bf16(al, bh[ct], acc[rt][ct], 0, 0, 0);
        acc[rt][ct] = __builtin_amdgcn_mfma_f32_16x16x32_bf16(ah, bl[ct], acc[rt][ct], 0, 0, 0);
      }
    }
  };

  // Pipeline: prefetch t+1 while computing t; consumer waits are counted
  // (16 younger loads in flight), never full drains.
  loadA(A0, 0); loadB(Bh0, Bl0, 0);
#pragma unroll 1
  for (int t = 0; t < 16; t += 2) {
    loadA(A1, t + 1); loadB(Bh1, Bl1, t + 1);
    compute(A0, Bh0, Bl0);
    if (t + 2 < 16) { loadA(A0, t + 2); loadB(Bh0, Bl0, t + 2); }
    compute(A1, Bh1, Bl1);
  }

  // ---- combine 8 K-partials: LDS float atomics into slab[64][66] ----
  __syncthreads();   // slab zero-init visible
  // C/D layout: token-in-tile = rt*16 + g*4 + r, expert = ct*16 + m (verified)
#pragma unroll
  for (int rt = 0; rt < 4; ++rt)
#pragma unroll
    for (int ct = 0; ct < 4; ++ct)
#pragma unroll
      for (int r = 0; r < 4; ++r)
        atomicAdd(&slab[(rt * 16 + g * 4 + r) * 66 + ct * 16 + m], acc[rt][ct][r]);
  __syncthreads();

  // softmax: 8 threads per token, 8 experts each (512 thr / 64 tokens)
  const int j = tid >> 3;        // token 0..63
  const int q = tid & 7;
  float v[8];
#pragma unroll
  for (int i = 0; i < 8; ++i) v[i] = bias[q * 8 + i] + slab[j * 66 + q * 8 + i];
  float best = v[0]; int bi = q * 8;
#pragma unroll
  for (int i = 1; i < 8; ++i)
    if (v[i] > best) { best = v[i]; bi = q * 8 + i; }
#pragma unroll
  for (int d = 1; d <= 4; d <<= 1) {   // reduce across the 8-lane token group
    float ob = __shfl_xor(best, d);
    int oi = __shfl_xor(bi, d);
    if (ob > best || (ob == best && oi < bi)) { best = ob; bi = oi; }
  }
  float ex[8], ssum = 0.f;
#pragma unroll
  for (int i = 0; i < 8; ++i) { ex[i] = __expf(v[i] - best); ssum += ex[i]; }
#pragma unroll
  for (int d = 1; d <= 4; d <<= 1) ssum += __shfl_xor(ssum, d);
  const float rs = 1.0f / ssum;

  const int gt = tok_base + j;
#pragma unroll
  for (int i = 0; i < 8; ++i) {
    float p = ex[i] * rs;
    out[(size_t)gt * 64 + q * 8 + i] = p;
    slab[j * 66 + q * 8 + i] = p;     // each thread rewrites exactly the slots it read
  }
  if (q == 0) {
    top_p[gt] = rs;                    // top prob = exp(best-best)/ssum
    top_i[gt] = bi;
    atomicAdd(&S_loc[bi], rs);         // LDS atomic
  }
  __syncthreads();
  if (tid < 64) {                      // per-expert partials for this block
    float sa = 0.f;
#pragma unroll
    for (int jj = 0; jj < ROWS; ++jj) sa += slab[jj * 66 + tid];
    Ppart[(size_t)blockIdx.x * 64 + tid] = sa;
    Spart[(size_t)blockIdx.x * 64 + tid] = S_loc[tid];
  }
}

// Kernel 2a: parallel stage-1 reduction of per-block partials.
// 16 blocks x 256 thr; block b reduces gemm-blocks [b*16, b*16+16).
__global__ __launch_bounds__(256) void aux1_kernel(const float* __restrict__ Spart,
                                                   const float* __restrict__ Ppart,
                                                   float* __restrict__ Sred,
                                                   float* __restrict__ Pred) {
  __shared__ float sS[4][64], sP[4][64];
  const int l = threadIdx.x & 63;
  const int c = threadIdx.x >> 6;
  const int base = blockIdx.x * 16 + c * 4;
  float ss = 0.f, pp = 0.f;
#pragma unroll
  for (int r = 0; r < 4; ++r) {
    ss += Spart[(size_t)(base + r) * 64 + l];
    pp += Ppart[(size_t)(base + r) * 64 + l];
  }
  sS[c][l] = ss; sP[c][l] = pp;
  __syncthreads();
  if (threadIdx.x < 64) {
    Sred[(size_t)blockIdx.x * 64 + l] = sS[0][l] + sS[1][l] + sS[2][l] + sS[3][l];
    Pred[(size_t)blockIdx.x * 64 + l] = sP[0][l] + sP[1][l] + sP[2][l] + sP[3][l];
  }
}

// Kernel 2b: finish reduction (16x64x2 = 8KB), emit Stot + aux loss scalar.
__global__ __launch_bounds__(64) void aux2_kernel(float* __restrict__ out,
                                                  const float* __restrict__ Sred,
                                                  const float* __restrict__ Pred,
                                                  float* __restrict__ Stot) {
  const int l = threadIdx.x;
  float Sv = 0.f, Pv = 0.f;
#pragma unroll
  for (int b = 0; b < 16; ++b) {
    Sv += Sred[b * 64 + l];
    Pv += Pred[b * 64 + l];
  }
  Stot[l] = Sv;
  float v = Sv * Pv;
#pragma unroll
  for (int d = 1; d <= 32; d <<= 1) v += __shfl_xor(v, d);
  if (l == 0) out[(size_t)T_TOK * E_NUM] = 0.01f * 64.0f * v / ((float)T_TOK * (float)T_TOK);
}

// Kernel 3: capacity masking. Fast path: expert top-prob sum <= 256 -> all tokens kept
// (cumsum monotone, probs > 0; probs <= 1 so cumsum over ~270 tokens << 256 in practice).
__global__ __launch_bounds__(256) void finalize_kernel(float* __restrict__ out,
                                                       const float* __restrict__ top_p,
                                                       const int* __restrict__ top_i,
                                                       const float* __restrict__ Stot) {
  int t = blockIdx.x * 256 + threadIdx.x;
  int e = top_i[t];
  float se = Stot[e];
  if (se > CAPF) {
    float p = top_p[t];
    float G = 0.f;
    for (int u = 0; u < T_TOK; ++u) {
      if (top_i[u] == e) {
        float q = top_p[u];
        if (q > p || (q == p && u <= t)) G += q;
      }
    }
    if (G > CAPF) {
      float4 z = {0.f, 0.f, 0.f, 0.f};
      float4* row = (float4*)(out + (size_t)t * 64);
#pragma unroll
      for (int i = 0; i < 16; ++i) row[i] = z;
    }
  }
}

extern "C" void kernel_launch(void* const* d_in, const int* in_sizes, int n_in,
                              void* d_out, int out_size, void* d_ws, size_t ws_size,
                              hipStream_t stream) {
  const float* x = (const float*)d_in[0];
  const float* W = (const float*)d_in[1];
  const float* b = (const float*)d_in[2];
  float* out = (float*)d_out;

  // ws layout (~1.3 MB)
  u16* Wp = (u16*)d_ws;                                   // 512 KB
  u16* Wlp = Wp + (size_t)E_NUM * D_DIM;                  // 512 KB
  float* top_p = (float*)(Wlp + (size_t)E_NUM * D_DIM);   // 64 KB
  int* top_i = (int*)(top_p + T_TOK);                     // 64 KB
  float* Spart = (float*)(top_i + T_TOK);                 // 64 KB
  float* Ppart = Spart + (size_t)NBLK * 64;               // 64 KB
  float* Sred = Ppart + (size_t)NBLK * 64;                // 4 KB
  float* Pred = Sred + 16 * 64;                           // 4 KB
  float* Stot = Pred + 16 * 64;                           // 256 B

  prep_kernel<<<128, 256, 0, stream>>>(W, Wp, Wlp);
  gemm_softmax<<<NBLK, 512, 0, stream>>>(x, Wp, Wlp, b, out, Spart, Ppart, top_p, top_i);
  aux1_kernel<<<16, 256, 0, stream>>>(Spart, Ppart, Sred, Pred);
  aux2_kernel<<<1, 64, 0, stream>>>(out, Sred, Pred, Stot);
  finalize_kernel<<<T_TOK / 256, 256, 0, stream>>>(out, top_p, top_i, Stot);
}

// Round 5
// 414.382 us; speedup vs baseline: 1.0108x; 1.0108x over previous
//
#include <hip/hip_runtime.h>
#include <stdint.h>

// Problem constants (fixed by reference setup_inputs)
#define D_DIM 4096      // hidden dim (K)
#define E_NUM 64        // experts (N)
#define T_TOK 16384     // tokens (M) = 4*4096
#define CAPF 256.0f     // expert_capacity = int(16384/64*1.0)
#define ROWS 32         // tokens per block
#define NBLK (T_TOK / ROWS)   // 512 blocks -> 2 blocks/CU

using bf16x8 = __attribute__((ext_vector_type(8))) short;
using f32x4  = __attribute__((ext_vector_type(4))) float;
typedef unsigned short u16;
typedef unsigned int u32;

// Truncation split: x == hi + lo exactly; lo then truncated to bf16 (err <= 2^-17 |x|).
__device__ __forceinline__ void cvt8(const float4 a, const float4 b, bf16x8& h, bf16x8& l) {
  float f[8] = {a.x, a.y, a.z, a.w, b.x, b.y, b.z, b.w};
#pragma unroll
  for (int i = 0; i < 8; ++i) {
    u32 u = __float_as_uint(f[i]);
    float lo = f[i] - __uint_as_float(u & 0xFFFF0000u);
    h[i] = (short)(u >> 16);
    l[i] = (short)(__float_as_uint(lo) >> 16);
  }
}

// Kernel 0: W (4096x64, [k][e]) -> Wp/Wlp packed in MFMA B-fragment order:
//   Wp[((kk*4 + ct)*64 + lane)*8 + i] = hi(W[kk*32 + (lane>>4)*8 + i][ct*16 + (lane&15)])
__global__ __launch_bounds__(256) void prep_kernel(const float* __restrict__ W,
                                                   u16* __restrict__ Wp, u16* __restrict__ Wlp) {
  const int t = blockIdx.x * 256 + threadIdx.x;   // 32768 threads, one 16B chunk each
  const int lane = t & 63;
  const int ct = (t >> 6) & 3;
  const int kk = t >> 8;
  const int e = ct * 16 + (lane & 15);
  const int k0 = kk * 32 + (lane >> 4) * 8;
  u32 hp[4], lp[4];
#pragma unroll
  for (int j = 0; j < 4; ++j) {
    u32 hh[2], ll[2];
#pragma unroll
    for (int q = 0; q < 2; ++q) {
      float w = W[(size_t)(k0 + 2 * j + q) * E_NUM + e];
      u32 u = __float_as_uint(w);
      float lo = w - __uint_as_float(u & 0xFFFF0000u);
      hh[q] = u >> 16;
      ll[q] = __float_as_uint(lo) >> 16;
    }
    hp[j] = hh[0] | (hh[1] << 16);
    lp[j] = ll[0] | (ll[1] << 16);
  }
  *(uint4*)(Wp  + (size_t)t * 8) = make_uint4(hp[0], hp[1], hp[2], hp[3]);
  *(uint4*)(Wlp + (size_t)t * 8) = make_uint4(lp[0], lp[1], lp[2], lp[3]);
}

// Kernel 1: barrier-free DMA-ring router GEMM + softmax + top-1.
// 32 tokens/block, 4 waves; wave kh owns K-quarter [kh*1024,+1024) = 32 chunks
// of 32 floats.  Each wave stages ITS OWN 32rows x 128B chunk into ITS OWN LDS
// ring buffer (2 x 4KB) via global_load_lds -> no __syncthreads in the K-loop;
// the only synchronization is a counted `s_waitcnt vmcnt(12)` that always
// leaves the next chunk's 4 DMAs + 8 B-loads in flight (never drains).  LDS
// reads are XOR-swizzled (byte ^= (row&7)<<4) with the inverse swizzle applied
// to the per-lane GLOBAL source address (linear LDS dest, guide rule 21), so
// ds_read_b128 is 2-way-conflict-free.  Rationale: four prior structures all
// plateaued at 140-165us with <7% on every pipe -- each paid a full memory
// latency per chunk (dependent waits drained the in-order vmcnt queue).
__global__ __launch_bounds__(256, 3) void gemm_softmax(
    const float* __restrict__ x, const u16* __restrict__ Wp, const u16* __restrict__ Wlp,
    const float* __restrict__ bias, float* __restrict__ out,
    float* __restrict__ Spart, float* __restrict__ Ppart,
    float* __restrict__ top_p, int* __restrict__ top_i) {
  __shared__ float smem[8192];   // 32KB: K-loop ring (4 waves x 2 x 4KB); epilogue slab alias
  __shared__ float S_loc[64];

  const int tid = threadIdx.x;
  const int lane = tid & 63;
  const int kh = tid >> 6;       // K-quarter (wave id)
  const int m = lane & 15;       // token-in-16 (A row)
  const int g = lane >> 4;       // k-octet
  const int tok_base = blockIdx.x * ROWS;

  f32x4 acc[2][4];               // 32 tokens x 64 experts / 64 lanes
#pragma unroll
  for (int rt = 0; rt < 2; ++rt)
#pragma unroll
    for (int ct = 0; ct < 4; ++ct) acc[rt][ct] = (f32x4){0.f, 0.f, 0.f, 0.f};

  // DMA source: lane covers row r8 (8 rows/dma), 16B col-group c8, with the
  // read-side XOR swizzle PRE-APPLIED (c8 ^ r8) so linear LDS = swizzled layout.
  const int r8 = lane >> 3;      // 0..7
  const int c8 = lane & 7;       // 0..7 (16B groups within 128B row-chunk)
  const float* gsrc = x + (size_t)(tok_base + r8) * D_DIM + kh * 1024 + 4 * (c8 ^ r8);
  char* ldsw = (char*)smem + kh * 8192;          // wave's private 8KB ring (bytes)
  // ds_read byte offsets within a 4KB buffer: row*128 + (g*32 [^+16]) ^ ((m&7)<<4)
  const int sw = (m & 7) << 4;
  const int off1 = (g * 32) ^ sw;
  const int off2 = (g * 32 + 16) ^ sw;

  auto DMA = [&](int c) {        // stage chunk c into buffer c&1 (4 x 1KB)
    char* dst = ldsw + (c & 1) * 4096;
    const float* s = gsrc + (size_t)c * 32;
#pragma unroll
    for (int i = 0; i < 4; ++i)
      __builtin_amdgcn_global_load_lds(
          (const __attribute__((address_space(1))) void*)(s + (size_t)i * 8 * D_DIM),
          (__attribute__((address_space(3))) void*)(dst + i * 1024), 16, 0, 0);
  };
  auto loadB = [&](bf16x8 (&bh)[4], bf16x8 (&bl)[4], int c) {
    const int kk = kh * 32 + c;
#pragma unroll
    for (int ct = 0; ct < 4; ++ct) {
      const size_t o = ((size_t)(kk * 4 + ct) * 64 + lane) * 8;
      bh[ct] = *(const bf16x8*)(Wp + o);
      bl[ct] = *(const bf16x8*)(Wlp + o);
    }
  };
  auto compute = [&](int c, const bf16x8 (&bh)[4], const bf16x8 (&bl)[4]) {
    const char* bp = (const char*)smem + kh * 8192 + (c & 1) * 4096;
#pragma unroll
    for (int rt = 0; rt < 2; ++rt) {
      const char* rp = bp + (rt * 16 + m) * 128;
      float4 a0 = *(const float4*)(rp + off1);
      float4 a1 = *(const float4*)(rp + off2);
      bf16x8 ah, al;
      cvt8(a0, a1, ah, al);
#pragma unroll
      for (int ct = 0; ct < 4; ++ct) {
        acc[rt][ct] = __builtin_amdgcn_mfma_f32_16x16x32_bf16(ah, bh[ct], acc[rt][ct], 0, 0, 0);
        acc[rt][ct] = __builtin_amdgcn_mfma_f32_16x16x32_bf16(al, bh[ct], acc[rt][ct], 0, 0, 0);
        acc[rt][ct] = __builtin_amdgcn_mfma_f32_16x16x32_bf16(ah, bl[ct], acc[rt][ct], 0, 0, 0);
      }
    }
  };

  bf16x8 Bh0[4], Bl0[4], Bh1[4], Bl1[4];
  DMA(0);
  loadB(Bh0, Bl0, 0);
#pragma unroll 1
  for (int c = 0; c < 32; c += 2) {
    // even half: prefetch c+1, consume c (buffer c&1, B0)
    DMA(c + 1);
    loadB(Bh1, Bl1, c + 1);
    __builtin_amdgcn_sched_barrier(0);
    asm volatile("s_waitcnt vmcnt(12)" ::: "memory");   // retire DMA(c)+B(c); keep 12 newest in flight
    __builtin_amdgcn_sched_barrier(0);
    compute(c, Bh0, Bl0);
    // odd half: prefetch c+2, consume c+1
    if (c + 2 < 32) {
      DMA(c + 2);
      loadB(Bh0, Bl0, c + 2);
      __builtin_amdgcn_sched_barrier(0);
      asm volatile("s_waitcnt vmcnt(12)" ::: "memory");
      __builtin_amdgcn_sched_barrier(0);
    } else {
      __builtin_amdgcn_sched_barrier(0);
      asm volatile("s_waitcnt vmcnt(0)" ::: "memory");  // final drain, once
      __builtin_amdgcn_sched_barrier(0);
    }
    compute(c + 1, Bh1, Bl1);
  }

  // ---- epilogue: combine 4 K-quarters into slab[32][66] (aliases the ring) ----
  __syncthreads();                       // all waves done with their ring regions
  for (int i = tid; i < 32 * 66; i += 256) smem[i] = 0.f;
  if (tid < 64) S_loc[tid] = 0.f;
  __syncthreads();
  // C/D layout: token-in-tile = rt*16 + g*4 + r, expert = ct*16 + m (verified)
#pragma unroll
  for (int rt = 0; rt < 2; ++rt)
#pragma unroll
    for (int ct = 0; ct < 4; ++ct)
#pragma unroll
      for (int r = 0; r < 4; ++r)
        atomicAdd(&smem[(rt * 16 + g * 4 + r) * 66 + ct * 16 + m], acc[rt][ct][r]);
  __syncthreads();

  // softmax: 8 threads per token, 8 experts each (256 thr / 32 tokens)
  const int j = tid >> 3;
  const int q = tid & 7;
  float v[8];
#pragma unroll
  for (int i = 0; i < 8; ++i) v[i] = bias[q * 8 + i] + smem[j * 66 + q * 8 + i];
  float best = v[0]; int bi = q * 8;
#pragma unroll
  for (int i = 1; i < 8; ++i)
    if (v[i] > best) { best = v[i]; bi = q * 8 + i; }
#pragma unroll
  for (int d = 1; d <= 4; d <<= 1) {   // reduce across the 8-lane token group
    float ob = __shfl_xor(best, d);
    int oi = __shfl_xor(bi, d);
    if (ob > best || (ob == best && oi < bi)) { best = ob; bi = oi; }
  }
  float ex[8], ssum = 0.f;
#pragma unroll
  for (int i = 0; i < 8; ++i) { ex[i] = __expf(v[i] - best); ssum += ex[i]; }
#pragma unroll
  for (int d = 1; d <= 4; d <<= 1) ssum += __shfl_xor(ssum, d);
  const float rs = 1.0f / ssum;

  const int gt = tok_base + j;
#pragma unroll
  for (int i = 0; i < 8; ++i) {
    float p = ex[i] * rs;
    out[(size_t)gt * 64 + q * 8 + i] = p;
    smem[j * 66 + q * 8 + i] = p;     // each thread rewrites exactly the slots it read
  }
  if (q == 0) {
    top_p[gt] = rs;                    // top prob = exp(best-best)/ssum
    top_i[gt] = bi;
    atomicAdd(&S_loc[bi], rs);         // LDS atomic
  }
  __syncthreads();
  if (tid < 64) {                      // per-expert partials for this block
    float sa = 0.f;
#pragma unroll
    for (int jj = 0; jj < ROWS; ++jj) sa += smem[jj * 66 + tid];
    Ppart[(size_t)blockIdx.x * 64 + tid] = sa;
    Spart[(size_t)blockIdx.x * 64 + tid] = S_loc[tid];
  }
}

// Kernel 2a: parallel stage-1 reduction of per-block partials.
// 16 blocks x 256 thr; block b reduces gemm-blocks [b*32, b*32+32).
__global__ __launch_bounds__(256) void aux1_kernel(const float* __restrict__ Spart,
                                                   const float* __restrict__ Ppart,
                                                   float* __restrict__ Sred,
                                                   float* __restrict__ Pred) {
  __shared__ float sS[4][64], sP[4][64];
  const int l = threadIdx.x & 63;
  const int c = threadIdx.x >> 6;
  const int base = blockIdx.x * 32 + c * 8;
  float ss = 0.f, pp = 0.f;
#pragma unroll
  for (int r = 0; r < 8; ++r) {
    ss += Spart[(size_t)(base + r) * 64 + l];
    pp += Ppart[(size_t)(base + r) * 64 + l];
  }
  sS[c][l] = ss; sP[c][l] = pp;
  __syncthreads();
  if (threadIdx.x < 64) {
    Sred[(size_t)blockIdx.x * 64 + l] = sS[0][l] + sS[1][l] + sS[2][l] + sS[3][l];
    Pred[(size_t)blockIdx.x * 64 + l] = sP[0][l] + sP[1][l] + sP[2][l] + sP[3][l];
  }
}

// Kernel 2b: finish reduction (16x64x2 = 8KB), emit Stot + aux loss scalar.
__global__ __launch_bounds__(64) void aux2_kernel(float* __restrict__ out,
                                                  const float* __restrict__ Sred,
                                                  const float* __restrict__ Pred,
                                                  float* __restrict__ Stot) {
  const int l = threadIdx.x;
  float Sv = 0.f, Pv = 0.f;
#pragma unroll
  for (int b = 0; b < 16; ++b) {
    Sv += Sred[b * 64 + l];
    Pv += Pred[b * 64 + l];
  }
  Stot[l] = Sv;
  float v = Sv * Pv;
#pragma unroll
  for (int d = 1; d <= 32; d <<= 1) v += __shfl_xor(v, d);
  if (l == 0) out[(size_t)T_TOK * E_NUM] = 0.01f * 64.0f * v / ((float)T_TOK * (float)T_TOK);
}

// Kernel 3: capacity masking. Fast path: expert top-prob sum <= 256 -> all tokens kept
// (cumsum monotone, probs > 0). Exact O(T) scan only if an expert overflows.
__global__ __launch_bounds__(256) void finalize_kernel(float* __restrict__ out,
                                                       const float* __restrict__ top_p,
                                                       const int* __restrict__ top_i,
                                                       const float* __restrict__ Stot) {
  int t = blockIdx.x * 256 + threadIdx.x;
  int e = top_i[t];
  float se = Stot[e];
  if (se > CAPF) {
    float p = top_p[t];
    float G = 0.f;
    for (int u = 0; u < T_TOK; ++u) {
      if (top_i[u] == e) {
        float q = top_p[u];
        if (q > p || (q == p && u <= t)) G += q;
      }
    }
    if (G > CAPF) {
      float4 z = {0.f, 0.f, 0.f, 0.f};
      float4* row = (float4*)(out + (size_t)t * 64);
#pragma unroll
      for (int i = 0; i < 16; ++i) row[i] = z;
    }
  }
}

extern "C" void kernel_launch(void* const* d_in, const int* in_sizes, int n_in,
                              void* d_out, int out_size, void* d_ws, size_t ws_size,
                              hipStream_t stream) {
  const float* x = (const float*)d_in[0];
  const float* W = (const float*)d_in[1];
  const float* b = (const float*)d_in[2];
  float* out = (float*)d_out;

  // ws layout (~1.4 MB)
  u16* Wp = (u16*)d_ws;                                   // 512 KB
  u16* Wlp = Wp + (size_t)E_NUM * D_DIM;                  // 512 KB
  float* top_p = (float*)(Wlp + (size_t)E_NUM * D_DIM);   // 64 KB
  int* top_i = (int*)(top_p + T_TOK);                     // 64 KB
  float* Spart = (float*)(top_i + T_TOK);                 // 128 KB
  float* Ppart = Spart + (size_t)NBLK * 64;               // 128 KB
  float* Sred = Ppart + (size_t)NBLK * 64;                // 4 KB
  float* Pred = Sred + 16 * 64;                           // 4 KB
  float* Stot = Pred + 16 * 64;                           // 256 B

  prep_kernel<<<128, 256, 0, stream>>>(W, Wp, Wlp);
  gemm_softmax<<<NBLK, 256, 0, stream>>>(x, Wp, Wlp, b, out, Spart, Ppart, top_p, top_i);
  aux1_kernel<<<16, 256, 0, stream>>>(Spart, Ppart, Sred, Pred);
  aux2_kernel<<<1, 64, 0, stream>>>(out, Sred, Pred, Stot);
  finalize_kernel<<<T_TOK / 256, 256, 0, stream>>>(out, top_p, top_i, Stot);
}